// Round 3
// baseline (1265.887 us; speedup 1.0000x reference)
//
#include <hip/hip_runtime.h>
#include <hip/hip_bf16.h>
#include <stdint.h>
#include <math.h>

typedef __bf16 bf16_t;
typedef __bf16 bf16x8 __attribute__((ext_vector_type(8)));
typedef __bf16 bf16x4 __attribute__((ext_vector_type(4)));
typedef float floatx4 __attribute__((ext_vector_type(4)));

#define NN 8192   // nodes
#define DD 512    // model dim
#define FF 2048   // ffn dim
#define MM 4096   // masked nodes
#define KK 128    // genes per masked node

// sh = log2(elements per 16B vector)
template<typename T> struct V16;
template<> struct V16<bf16_t> { using t = bf16x8;  static const int sh = 3; };
template<> struct V16<float>  { using t = floatx4; static const int sh = 2; };

// ---------------------------------------------------------------------------
// async global->LDS 16B copy (dst must be wave-uniform base + lane*16 layout)
// ---------------------------------------------------------------------------
__device__ __forceinline__ void async_copy16(const void* g, void* l) {
    __builtin_amdgcn_global_load_lds(
        (const __attribute__((address_space(1))) void*)(uintptr_t)g,
        (__attribute__((address_space(3))) void*)(uint32_t)(uintptr_t)l,
        16, 0, 0);
}

// ---------------------------------------------------------------------------
// NT GEMM: C[M x Nc] = A[M x Kd] @ B[Nc x Kd]^T   (bf16 in, fp32 accum)
// EPI: 0=none, 1=scale, 2=+bias, 3=+bias+gelu(exact),
//      4=exp(v*scale) + per-row partial-sum atomicAdd into denom[]
// Split-K via gridDim.z: block z writes C + z*partStride (combined downstream)
// Strided A/B/C via ldA/ldB/ldC. Epilogue stores via LDS => 16B coalesced.
// 128x128 tile, BK=32, 256 threads (4 waves 2x2), mfma_f32_16x16x32_bf16
// ---------------------------------------------------------------------------
template<int EPI, typename OT>
__global__ __launch_bounds__(256)
void gemm_nt(const bf16_t* __restrict__ A, const bf16_t* __restrict__ B,
             OT* __restrict__ C,
             int M, int Nc, int Kd, int ldA, int ldB, int ldC,
             long partStride, float scale, const float* __restrict__ bias,
             float* __restrict__ denom)
{
    __shared__ char smem[16384];
    bf16_t* As = (bf16_t*)smem;
    bf16_t* Bs = (bf16_t*)(smem + 8192);

    const int tid  = threadIdx.x;
    const int lane = tid & 63;
    const int wave = tid >> 6;
    const int wm   = (wave >> 1) << 6;
    const int wn   = (wave & 1) << 6;
    const int quad = lane >> 4;
    const int l16  = lane & 15;

    // bijective XCD-contiguous swizzle (all our grids have nwg % 8 == 0)
    const int gx   = gridDim.x;
    const int nwg  = gx * gridDim.y;
    const int orig = blockIdx.y * gx + blockIdx.x;
    const int swz  = (orig & 7) * (nwg >> 3) + (orig >> 3);
    const long bm  = (long)(swz % gx) * 128;
    const long bn  = (long)(swz / gx) * 128;

    const int  kchunk = Kd / gridDim.z;
    const long kBeg   = (long)blockIdx.z * kchunk;
    OT* __restrict__ Co = C + (long)blockIdx.z * partStride;

    const int t0 = tid, t1 = tid + 256;
    const bf16_t* pA0 = A + (bm + (t0 >> 2)) * (long)ldA + (t0 & 3) * 8 + kBeg;
    const bf16_t* pA1 = A + (bm + (t1 >> 2)) * (long)ldA + (t1 & 3) * 8 + kBeg;
    const bf16_t* pB0 = B + (bn + (t0 >> 2)) * (long)ldB + (t0 & 3) * 8 + kBeg;
    const bf16_t* pB1 = B + (bn + (t1 >> 2)) * (long)ldB + (t1 & 3) * 8 + kBeg;
    bf16_t* lA0 = &As[t0 * 8];
    bf16_t* lA1 = &As[t1 * 8];
    bf16_t* lB0 = &Bs[t0 * 8];
    bf16_t* lB1 = &Bs[t1 * 8];

    floatx4 acc[4][4] = {};

    for (long k0 = 0; k0 < kchunk; k0 += 32) {
        async_copy16(pA0 + k0, lA0);
        async_copy16(pA1 + k0, lA1);
        async_copy16(pB0 + k0, lB0);
        async_copy16(pB1 + k0, lB1);
        __syncthreads();

        bf16x8 af[4], bfr[4];
#pragma unroll
        for (int i = 0; i < 4; i++) {
            af[i]  = *(const bf16x8*)&As[(wm + i * 16 + l16) * 32 + quad * 8];
            bfr[i] = *(const bf16x8*)&Bs[(wn + i * 16 + l16) * 32 + quad * 8];
        }
#pragma unroll
        for (int mi = 0; mi < 4; mi++)
#pragma unroll
            for (int ni = 0; ni < 4; ni++)
                acc[mi][ni] = __builtin_amdgcn_mfma_f32_16x16x32_bf16(
                    af[mi], bfr[ni], acc[mi][ni], 0, 0, 0);
        __syncthreads();
    }

    // -----------------------------------------------------------------------
    // epilogue through LDS: acc frag layout (col=lane&15, row=quad*4+reg,
    // verified m89/m91) -> LDS [32][128] OT tile -> 16B coalesced stores.
    // rows 0-15 = waves wm=0 (mi-slice), rows 16-31 = waves wm=64.
    // -----------------------------------------------------------------------
    OT* sm = (OT*)smem;               // 32*128*sizeof(OT) <= 16384
    const int g = wm >> 6;
#pragma unroll
    for (int mi = 0; mi < 4; mi++) {
        if (mi) __syncthreads();
        const long rbase = bm + wm + mi * 16 + quad * 4;
        if (EPI == 4) {
#pragma unroll
            for (int r = 0; r < 4; r++) {
                float rsum = 0.0f;
#pragma unroll
                for (int ni = 0; ni < 4; ni++) {
                    float v = __expf(acc[mi][ni][r] * scale);
                    rsum += v;
                    sm[(g * 16 + quad * 4 + r) * 128 + wn + ni * 16 + l16] = (OT)v;
                }
                rsum += __shfl_xor(rsum, 1);
                rsum += __shfl_xor(rsum, 2);
                rsum += __shfl_xor(rsum, 4);
                rsum += __shfl_xor(rsum, 8);
                if (l16 == 0) atomicAdd(denom + rbase + r, rsum);
            }
        } else {
#pragma unroll
            for (int ni = 0; ni < 4; ni++) {
                float bv = (EPI >= 2) ? bias[bn + wn + ni * 16 + l16] : 0.0f;
#pragma unroll
                for (int r = 0; r < 4; r++) {
                    float v = acc[mi][ni][r];
                    if (EPI == 1) v *= scale;
                    if (EPI >= 2) v += bv;
                    if (EPI == 3) v = 0.5f * v * (1.0f + erff(v * 0.70710678118f));
                    sm[(g * 16 + quad * 4 + r) * 128 + wn + ni * 16 + l16] = (OT)v;
                }
            }
        }
        __syncthreads();
        // coalesced store: 32 rows x 128 cols, 16B per thread per pass
        typedef typename V16<OT>::t VT;
        const int VSH = V16<OT>::sh;          // log2 elems per 16B
        const int VEC = 1 << VSH;
        const int NP  = (32 * 128) / (256 * VEC);   // 2 (bf16) / 4 (f32)
#pragma unroll
        for (int p = 0; p < NP; p++) {
            const int vid  = p * 256 + tid;
            const int lrow = vid >> (7 - VSH);      // vid / (128/VEC)
            const int vcol = vid & ((128 >> VSH) - 1);
            const long grow = bm + (lrow >> 4) * 64 + mi * 16 + (lrow & 15);
            *(VT*)&Co[grow * (long)ldC + bn + vcol * VEC] =
                *(const VT*)&sm[lrow * 128 + vcol * VEC];
        }
    }
}

template<int EPI, typename OT>
static void launch_gemm(const bf16_t* A, const bf16_t* B, OT* C,
                        int M, int Nc, int Kd, int lda, int ldb, int ldc,
                        int splitk, long partStride, float scale,
                        const float* bias, float* denom, hipStream_t s)
{
    dim3 g(M / 128, Nc / 128, splitk);
    gemm_nt<EPI, OT><<<g, 256, 0, s>>>(A, B, C, M, Nc, Kd, lda, ldb, ldc,
                                       partStride, scale, bias, denom);
}

// ---------------------------------------------------------------------------
// transpose + f32->bf16 convert: in[R x C] f32 -> out[C x R] bf16
// ---------------------------------------------------------------------------
__global__ __launch_bounds__(256)
void transpose_f2b(const float* __restrict__ in, bf16_t* __restrict__ out,
                   int R, int C)
{
    __shared__ float tile[32][33];
    const int bx = blockIdx.x * 32;  // col base in 'in'
    const int by = blockIdx.y * 32;  // row base in 'in'
    const int tx = threadIdx.x, ty = threadIdx.y;  // (32, 8)
#pragma unroll
    for (int i = 0; i < 32; i += 8)
        tile[ty + i][tx] = in[(long)(by + ty + i) * C + bx + tx];
    __syncthreads();
#pragma unroll
    for (int i = 0; i < 32; i += 8)
        out[(long)(bx + ty + i) * R + by + tx] = (bf16_t)tile[tx][ty + i];
}

// ---------------------------------------------------------------------------
// strided bf16 transpose: in[R x C] (row stride ldin) -> out[C x R]
// ---------------------------------------------------------------------------
__global__ __launch_bounds__(256)
void transpose_b2b(const bf16_t* __restrict__ in, bf16_t* __restrict__ out,
                   int R, int C, int ldin)
{
    __shared__ bf16_t tile[32][34];
    const int bx = blockIdx.x * 32;
    const int by = blockIdx.y * 32;
    const int tx = threadIdx.x, ty = threadIdx.y;  // (32, 8)
#pragma unroll
    for (int i = 0; i < 32; i += 8)
        tile[ty + i][tx] = in[(long)(by + ty + i) * ldin + bx + tx];
    __syncthreads();
#pragma unroll
    for (int i = 0; i < 32; i += 8)
        out[(long)(bx + ty + i) * R + by + tx] = tile[tx][ty + i];
}

// ---------------------------------------------------------------------------
// encoder attn-weights: out_f32[row] = P_unnorm_bf16[row] / denom[row]
// ---------------------------------------------------------------------------
__global__ __launch_bounds__(256)
void encw_norm(const bf16_t* __restrict__ P, const float* __restrict__ denom,
               float* __restrict__ out)
{
    const long row = blockIdx.x;
    const float inv = 1.0f / denom[row];
    const bf16_t* p = P + row * (long)NN;
    float* q = out + row * (long)NN;
    const int tid = threadIdx.x;
#pragma unroll
    for (int i = 0; i < 4; i++) {
        const int o = (tid + i * 256) * 8;
        bf16x8 v = *(const bf16x8*)(p + o);
        float4 lo, hi;
        lo.x = (float)v[0] * inv; lo.y = (float)v[1] * inv;
        lo.z = (float)v[2] * inv; lo.w = (float)v[3] * inv;
        hi.x = (float)v[4] * inv; hi.y = (float)v[5] * inv;
        hi.z = (float)v[6] * inv; hi.w = (float)v[7] * inv;
        *(float4*)(q + o)     = lo;
        *(float4*)(q + o + 4) = hi;
    }
}

__global__ __launch_bounds__(256)
void zero_f32(float* __restrict__ p)
{
    p[blockIdx.x * 256 + threadIdx.x] = 0.0f;
}

// ---------------------------------------------------------------------------
// LayerNorm(sum(NP partials)*rowscale? + colbias? + b) * g + be
// emits bf16 (ob) and f32 (of). one wave per row of DD=512
// ---------------------------------------------------------------------------
template<int NP, bool RS, bool CB>
__global__ __launch_bounds__(64)
void add_ln_gen(const float* __restrict__ a, long pstride,
                const float* __restrict__ rs, const float* __restrict__ cb,
                const float* __restrict__ b,
                const float* __restrict__ g, const float* __restrict__ be,
                bf16_t* __restrict__ ob, float* __restrict__ of)
{
    const long row = blockIdx.x;
    const int lane = threadIdx.x;
    const long base = row * DD + lane * 8;
    const float irs = RS ? (1.0f / rs[row]) : 1.0f;
    float v[8], s = 0.0f, s2 = 0.0f;
#pragma unroll
    for (int j = 0; j < 8; j++) {
        float t = 0.0f;
#pragma unroll
        for (int p = 0; p < NP; p++) t += a[base + j + p * pstride];
        t *= irs;
        if (CB) t += cb[lane * 8 + j];
        t += b[base + j];
        v[j] = t;
        s += t; s2 += t * t;
    }
#pragma unroll
    for (int off = 32; off > 0; off >>= 1) {
        s  += __shfl_xor(s,  off);
        s2 += __shfl_xor(s2, off);
    }
    const float mu  = s * (1.0f / DD);
    const float var = s2 * (1.0f / DD) - mu * mu;
    const float inv = rsqrtf(var + 1e-5f);
    bf16x8 o;
#pragma unroll
    for (int j = 0; j < 8; j++) {
        float r = (v[j] - mu) * inv * g[lane * 8 + j] + be[lane * 8 + j];
        o[j] = (bf16_t)r;
        of[base + j] = r;
    }
    *(bf16x8*)(ob + base) = o;
}

// ---------------------------------------------------------------------------
// use_x construction, masked scatter/gather (f32 I/O, int32 indices)
// ---------------------------------------------------------------------------
__global__ __launch_bounds__(256)
void build_usex(const float* __restrict__ x, bf16_t* __restrict__ ub,
                float* __restrict__ uf)
{
    const long i = ((long)blockIdx.x * 256 + threadIdx.x) * 4;
    const float4 v = *(const float4*)(x + i);
    *(float4*)(uf + i) = v;
    bf16x4 o = { (bf16_t)v.x, (bf16_t)v.y, (bf16_t)v.z, (bf16_t)v.w };
    *(bf16x4*)(ub + i) = o;
}

__global__ __launch_bounds__(256)
void scatter_zero(bf16_t* __restrict__ ub, float* __restrict__ uf,
                  const int* __restrict__ mn, const int* __restrict__ gi)
{
    const int i = blockIdx.x * 256 + threadIdx.x;   // grid = MM*KK/256
    const long idx = (long)mn[i >> 7] * DD + gi[i];
    ub[idx] = (bf16_t)0.0f;
    uf[idx] = 0.0f;
}

__global__ __launch_bounds__(256)
void gather_mk(const float* __restrict__ src, const int* __restrict__ mn,
               const int* __restrict__ gi, float* __restrict__ dst)
{
    const int i = blockIdx.x * 256 + threadIdx.x;
    dst[i] = src[(long)mn[i >> 7] * DD + gi[i]];
}

// head split-K combine + bias folded into the masked gather (2 partials)
__global__ __launch_bounds__(256)
void gather_head(const float* __restrict__ p1, long pstride,
                 const float* __restrict__ hb, const int* __restrict__ mn,
                 const int* __restrict__ gi, float* __restrict__ dst)
{
    const int i = blockIdx.x * 256 + threadIdx.x;
    const int col = gi[i];
    const long idx = (long)mn[i >> 7] * DD + col;
    dst[i] = p1[idx] + p1[idx + pstride] + hb[col];
}

// ---------------------------------------------------------------------------
extern "C" void kernel_launch(void* const* d_in, const int* in_sizes, int n_in,
                              void* d_out, int out_size, void* d_ws, size_t ws_size,
                              hipStream_t stream)
{
    const float* x      = (const float*)d_in[0];
    const int*   mn     = (const int*)d_in[1];
    const int*   gi     = (const int*)d_in[2];
    const float* Wq_e   = (const float*)d_in[3];
    const float* Wk_e   = (const float*)d_in[4];
    const float* Wv_e   = (const float*)d_in[5];
    const float* ln1_g  = (const float*)d_in[6];
    const float* ln1_b  = (const float*)d_in[7];
    const float* ff_W1  = (const float*)d_in[8];
    const float* ff_b1  = (const float*)d_in[9];
    const float* ff_W2  = (const float*)d_in[10];
    const float* ff_b2  = (const float*)d_in[11];
    const float* ln2_g  = (const float*)d_in[12];
    const float* ln2_b  = (const float*)d_in[13];
    const float* Wq_d   = (const float*)d_in[14];
    const float* Wk_d   = (const float*)d_in[15];
    const float* Wv_d   = (const float*)d_in[16];
    const float* ln3_g  = (const float*)d_in[17];
    const float* ln3_b  = (const float*)d_in[18];
    const float* ln4_g  = (const float*)d_in[19];
    const float* ln4_b  = (const float*)d_in[20];
    const float* head_W = (const float*)d_in[21];
    const float* head_b = (const float*)d_in[22];

    float* outf     = (float*)d_out;
    float* o_xinit  = outf;                           // [MM*KK]
    float* o_xrecon = outf + (size_t)MM * KK;         // [MM*KK]
    float* o_encw   = outf + (size_t)2 * MM * KK;     // [NN*NN]
    float* o_recon  = o_encw + (size_t)NN * NN;       // [NN*DD]

    // workspace carve-up (256B aligned) with lifetime aliasing
    char* ws = (char*)d_ws;
    size_t off = 0;
    auto alloc = [&](size_t bytes) -> void* {
        void* p = ws + off;
        off += (bytes + 255) & ~(size_t)255;
        return p;
    };
    const size_t NDb = (size_t)NN * DD * sizeof(bf16_t);   // 8 MiB
    const size_t NDf = (size_t)NN * DD * sizeof(float);    // 16 MiB
    const long   NDe = (long)NN * DD;                      // partial stride

    bf16_t* usex_b = (bf16_t*)alloc(NDb);
    bf16_t* qkv_b  = (bf16_t*)alloc((size_t)NN * 3 * DD * 2);  // 24 MiB
    bf16_t* vt_b   = (bf16_t*)alloc(NDb);
    bf16_t* hid_b  = (bf16_t*)alloc(NDb);
    float*  usex_f = (float*)alloc(NDf);
    float*  resA_f = (float*)alloc(NDf);
    float*  part_f = (float*)alloc(4 * NDf);               // 64 MiB split-K
    bf16_t* wt_qe  = (bf16_t*)alloc((size_t)DD * DD * 2);  // qe/ke/ve contiguous
    bf16_t* wt_ke  = (bf16_t*)alloc((size_t)DD * DD * 2);
    bf16_t* wt_ve  = (bf16_t*)alloc((size_t)DD * DD * 2);
    bf16_t* wt_qd  = (bf16_t*)alloc((size_t)DD * DD * 2);  // qd/kd/vd contiguous
    bf16_t* wt_kd  = (bf16_t*)alloc((size_t)DD * DD * 2);
    bf16_t* wt_vd  = (bf16_t*)alloc((size_t)DD * DD * 2);
    bf16_t* wt_h   = (bf16_t*)alloc((size_t)DD * DD * 2);
    bf16_t* w1t    = (bf16_t*)alloc((size_t)DD * FF * 2);
    bf16_t* w2t    = (bf16_t*)alloc((size_t)FF * DD * 2);
    float*  denom  = (float*)alloc((size_t)NN * sizeof(float));
    bf16_t* scores = (bf16_t*)alloc((size_t)NN * NN * 2);  // 128 MiB
    // aliases (disjoint lifetimes):
    bf16_t* t1_b   = scores;           // [NN*FF] bf16, FFN mid — attn phases done
    float*  resB_f = usex_f;           // usex_f dead after ln1; resB born at ln2
    (void)ws_size; (void)in_sizes; (void)n_in; (void)out_size;
    (void)wt_ke; (void)wt_ve; (void)wt_kd; (void)wt_vd;

    auto tr = [&](const float* in, bf16_t* o, int R, int C) {
        transpose_f2b<<<dim3(C / 32, R / 32), dim3(32, 8), 0, stream>>>(in, o, R, C);
    };
    const float SC = 0.04419417382f;  // 1/sqrt(512)

    // 0. weights -> transposed bf16 (q/k/v trios contiguous => fused-QKV B)
    tr(Wq_e, wt_qe, DD, DD);  tr(Wk_e, wt_ke, DD, DD);  tr(Wv_e, wt_ve, DD, DD);
    tr(Wq_d, wt_qd, DD, DD);  tr(Wk_d, wt_kd, DD, DD);  tr(Wv_d, wt_vd, DD, DD);
    tr(head_W, wt_h, DD, DD); tr(ff_W1, w1t, DD, FF);   tr(ff_W2, w2t, FF, DD);

    // 1. use_x (bf16 + f32) with masked zeros; x_init gather (exact f32)
    build_usex<<<NN * DD / 1024, 256, 0, stream>>>(x, usex_b, usex_f);
    scatter_zero<<<MM * KK / 256, 256, 0, stream>>>(usex_b, usex_f, mn, gi);
    gather_mk<<<MM * KK / 256, 256, 0, stream>>>(x, mn, gi, o_xinit);

    // 2. encoder attention
    //   fused QKV: [NN x 1536] = usex @ [Wq|Wk|Wv]
    launch_gemm<0, bf16_t>(usex_b, wt_qe, qkv_b,
                           NN, 3 * DD, DD, DD, DD, 3 * DD, 1, 0, 0.f, nullptr,
                           nullptr, stream);
    transpose_b2b<<<dim3(DD / 32, NN / 32), dim3(32, 8), 0, stream>>>(
        qkv_b + 2 * DD, vt_b, NN, DD, 3 * DD);        // V^T bf16 [DD x NN]
    zero_f32<<<NN / 256, 256, 0, stream>>>(denom);
    //   P_unnorm = exp(QK^T/sqrt(D)); row partial sums -> denom
    launch_gemm<4, bf16_t>(qkv_b, qkv_b + DD, scores,
                           NN, NN, DD, 3 * DD, 3 * DD, NN, 1, 0, SC, nullptr,
                           denom, stream);
    encw_norm<<<NN, 256, 0, stream>>>(scores, denom, o_encw);
    //   O_unnorm = P_unnorm @ V  (split-K=4; scale+combine in LN)
    launch_gemm<0, float>(scores, vt_b, part_f,
                          NN, DD, NN, NN, NN, DD, 4, NDe, 0.f, nullptr,
                          nullptr, stream);
    add_ln_gen<4, true, false><<<NN, 64, 0, stream>>>(
        part_f, NDe, denom, nullptr, usex_f, ln1_g, ln1_b, hid_b, resA_f);

    // 3. encoder FFN (scores dead -> t1 alias live)
    launch_gemm<3, bf16_t>(hid_b, w1t, t1_b,
                           NN, FF, DD, DD, DD, FF, 1, 0, 0.f, ff_b1,
                           nullptr, stream);
    launch_gemm<0, float>(t1_b, w2t, part_f,
                          NN, DD, FF, FF, FF, DD, 4, NDe, 0.f, nullptr,
                          nullptr, stream);
    add_ln_gen<4, false, true><<<NN, 64, 0, stream>>>(
        part_f, NDe, nullptr, ff_b2, resA_f, ln2_g, ln2_b, hid_b, resB_f);

    // 4. decoder attention (t1 dead -> scores alias live)
    launch_gemm<0, bf16_t>(hid_b, wt_qd, qkv_b,
                           NN, 3 * DD, DD, DD, DD, 3 * DD, 1, 0, 0.f, nullptr,
                           nullptr, stream);
    transpose_b2b<<<dim3(DD / 32, NN / 32), dim3(32, 8), 0, stream>>>(
        qkv_b + 2 * DD, vt_b, NN, DD, 3 * DD);
    zero_f32<<<NN / 256, 256, 0, stream>>>(denom);
    launch_gemm<4, bf16_t>(qkv_b, qkv_b + DD, scores,
                           NN, NN, DD, 3 * DD, 3 * DD, NN, 1, 0, SC, nullptr,
                           denom, stream);
    launch_gemm<0, float>(scores, vt_b, part_f,
                          NN, DD, NN, NN, NN, DD, 4, NDe, 0.f, nullptr,
                          nullptr, stream);
    add_ln_gen<4, true, false><<<NN, 64, 0, stream>>>(
        part_f, NDe, denom, nullptr, resB_f, ln3_g, ln3_b, hid_b, resA_f);

    // 5. decoder FFN (scores dead -> t1 alias live)
    launch_gemm<3, bf16_t>(hid_b, w1t, t1_b,
                           NN, FF, DD, DD, DD, FF, 1, 0, 0.f, ff_b1,
                           nullptr, stream);
    launch_gemm<0, float>(t1_b, w2t, part_f,
                          NN, DD, FF, FF, FF, DD, 4, NDe, 0.f, nullptr,
                          nullptr, stream);
    add_ln_gen<4, false, true><<<NN, 64, 0, stream>>>(
        part_f, NDe, nullptr, ff_b2, resA_f, ln4_g, ln4_b, hid_b, o_recon);

    // 6. head (split-K=2, bias+combine folded into gather)
    launch_gemm<0, float>(hid_b, wt_h, part_f,
                          NN, DD, DD, DD, DD, DD, 2, NDe, 0.f, nullptr,
                          nullptr, stream);
    gather_head<<<MM * KK / 256, 256, 0, stream>>>(part_f, NDe, head_b,
                                                   mn, gi, o_xrecon);
}

// Round 6
// 1093.351 us; speedup vs baseline: 1.1578x; 1.1578x over previous
//
#include <hip/hip_runtime.h>
#include <hip/hip_bf16.h>
#include <stdint.h>
#include <math.h>

typedef __bf16 bf16_t;
typedef __bf16 bf16x8 __attribute__((ext_vector_type(8)));
typedef __bf16 bf16x4 __attribute__((ext_vector_type(4)));
typedef float floatx4 __attribute__((ext_vector_type(4)));

#define NN 8192   // nodes
#define DD 512    // model dim
#define FF 2048   // ffn dim
#define MM 4096   // masked nodes
#define KK 128    // genes per masked node

// sh = log2(elements per 16B vector)
template<typename T> struct V16;
template<> struct V16<bf16_t> { using t = bf16x8;  static const int sh = 3; };
template<> struct V16<float>  { using t = floatx4; static const int sh = 2; };

// ---------------------------------------------------------------------------
// async global->LDS 16B copy (dst must be wave-uniform base + lane*16 layout)
// ---------------------------------------------------------------------------
__device__ __forceinline__ void async_copy16(const void* g, void* l) {
    __builtin_amdgcn_global_load_lds(
        (const __attribute__((address_space(1))) void*)(uintptr_t)g,
        (__attribute__((address_space(3))) void*)(uint32_t)(uintptr_t)l,
        16, 0, 0);
}

// ---------------------------------------------------------------------------
// NT GEMM: C[M x Nc] = A[M x Kd] @ B[Nc x Kd]^T   (bf16 in, fp32 accum)
// EPI: 0=none, 1=scale, 2=+bias, 3=+bias+gelu(exact),
//      4=exp(v*scale) + per-row partial-sum atomicAdd into denom[]
// Split-K via gridDim.z: block z writes C + z*partStride (combined downstream)
// Strided A/B/C via ldA/ldB/ldC. Epilogue stores via LDS => 16B coalesced.
// 128x128 tile, BK=32, 256 threads (4 waves 2x2), mfma_f32_16x16x32_bf16.
// K-loop: double-buffered LDS, ONE __syncthreads per K-step, next tile's
// global_load_lds issued BEFORE current compute so its HBM flight overlaps
// the MFMA phase. No inline asm / raw barriers — deadlock-impossible.
// ---------------------------------------------------------------------------
template<int EPI, typename OT>
__global__ __launch_bounds__(256, 3)
void gemm_nt(const bf16_t* __restrict__ A, const bf16_t* __restrict__ B,
             OT* __restrict__ C,
             int M, int Nc, int Kd, int ldA, int ldB, int ldC,
             long partStride, float scale, const float* __restrict__ bias,
             float* __restrict__ denom)
{
    __shared__ char smem[32768];
    bf16_t* As0 = (bf16_t*)smem;            // [128*32] per buffer
    bf16_t* As1 = As0 + 4096;
    bf16_t* Bs0 = As0 + 8192;
    bf16_t* Bs1 = As0 + 12288;

    const int tid  = threadIdx.x;
    const int lane = tid & 63;
    const int wave = tid >> 6;
    const int wm   = (wave >> 1) << 6;
    const int wn   = (wave & 1) << 6;
    const int quad = lane >> 4;
    const int l16  = lane & 15;

    // bijective XCD-contiguous swizzle (all our grids have nwg % 8 == 0)
    const int gx   = gridDim.x;
    const int nwg  = gx * gridDim.y;
    const int orig = blockIdx.y * gx + blockIdx.x;
    const int swz  = (orig & 7) * (nwg >> 3) + (orig >> 3);
    const long bm  = (long)(swz % gx) * 128;
    const long bn  = (long)(swz / gx) * 128;

    const int  kchunk = Kd / gridDim.z;
    const long kBeg   = (long)blockIdx.z * kchunk;
    OT* __restrict__ Co = C + (long)blockIdx.z * partStride;

    const int t0 = tid, t1 = tid + 256;
    const bf16_t* pA0 = A + (bm + (t0 >> 2)) * (long)ldA + (t0 & 3) * 8 + kBeg;
    const bf16_t* pA1 = A + (bm + (t1 >> 2)) * (long)ldA + (t1 & 3) * 8 + kBeg;
    const bf16_t* pB0 = B + (bn + (t0 >> 2)) * (long)ldB + (t0 & 3) * 8 + kBeg;
    const bf16_t* pB1 = B + (bn + (t1 >> 2)) * (long)ldB + (t1 & 3) * 8 + kBeg;

    floatx4 acc[4][4] = {};

    auto stage = [&](bf16_t* Ab, bf16_t* Bb, long k0) {
        async_copy16(pA0 + k0, Ab + t0 * 8);
        async_copy16(pA1 + k0, Ab + t1 * 8);
        async_copy16(pB0 + k0, Bb + t0 * 8);
        async_copy16(pB1 + k0, Bb + t1 * 8);
    };
    auto compute = [&](const bf16_t* Ab, const bf16_t* Bb) {
        bf16x8 af[4], bfr[4];
#pragma unroll
        for (int i = 0; i < 4; i++) {
            af[i]  = *(const bf16x8*)&Ab[(wm + i * 16 + l16) * 32 + quad * 8];
            bfr[i] = *(const bf16x8*)&Bb[(wn + i * 16 + l16) * 32 + quad * 8];
        }
#pragma unroll
        for (int mi = 0; mi < 4; mi++)
#pragma unroll
            for (int ni = 0; ni < 4; ni++)
                acc[mi][ni] = __builtin_amdgcn_mfma_f32_16x16x32_bf16(
                    af[mi], bfr[ni], acc[mi][ni], 0, 0, 0);
    };

    // nt is even for every GEMM in this net (min kchunk = 256 -> nt = 8).
    // WAR safety: buffer X written at step t+2 only after the barrier that
    // follows step t's compute (which read X). Each __syncthreads drains
    // vmcnt(0), so the buffer staged during this step is resident for next.
    const int nt = kchunk >> 5;
    stage(As0, Bs0, 0);
    __syncthreads();                       // buf0 resident
    long kk = 32;
    for (int t = 0; t < nt; t += 2) {
        // step t: stage buf1 (flight overlaps compute), compute buf0
        stage(As1, Bs1, kk); kk += 32;
        compute(As0, Bs0);
        __syncthreads();                   // buf1 resident; buf0 free
        // step t+1: stage buf0 (unless last), compute buf1
        if (t + 2 < nt) { stage(As0, Bs0, kk); kk += 32; }
        compute(As1, Bs1);
        __syncthreads();                   // buf0 resident; buf1 free
    }

    // -----------------------------------------------------------------------
    // epilogue through LDS: acc frag layout (col=lane&15, row=quad*4+reg,
    // verified m89/m91) -> LDS [32][128] OT tile -> 16B coalesced stores.
    // rows 0-15 = waves wm=0 (mi-slice), rows 16-31 = waves wm=64.
    // -----------------------------------------------------------------------
    OT* sm = (OT*)smem;               // 32*128*sizeof(OT) <= 16384
    const int g = wm >> 6;
#pragma unroll
    for (int mi = 0; mi < 4; mi++) {
        if (mi) __syncthreads();
        const long rbase = bm + wm + mi * 16 + quad * 4;
        if (EPI == 4) {
#pragma unroll
            for (int r = 0; r < 4; r++) {
                float rsum = 0.0f;
#pragma unroll
                for (int ni = 0; ni < 4; ni++) {
                    float v = __expf(acc[mi][ni][r] * scale);
                    rsum += v;
                    sm[(g * 16 + quad * 4 + r) * 128 + wn + ni * 16 + l16] = (OT)v;
                }
                rsum += __shfl_xor(rsum, 1);
                rsum += __shfl_xor(rsum, 2);
                rsum += __shfl_xor(rsum, 4);
                rsum += __shfl_xor(rsum, 8);
                if (l16 == 0) atomicAdd(denom + rbase + r, rsum);
            }
        } else {
#pragma unroll
            for (int ni = 0; ni < 4; ni++) {
                float bv = (EPI >= 2) ? bias[bn + wn + ni * 16 + l16] : 0.0f;
#pragma unroll
                for (int r = 0; r < 4; r++) {
                    float v = acc[mi][ni][r];
                    if (EPI == 1) v *= scale;
                    if (EPI >= 2) v += bv;
                    if (EPI == 3) v = 0.5f * v * (1.0f + erff(v * 0.70710678118f));
                    sm[(g * 16 + quad * 4 + r) * 128 + wn + ni * 16 + l16] = (OT)v;
                }
            }
        }
        __syncthreads();
        // coalesced store: 32 rows x 128 cols, 16B per thread per pass
        typedef typename V16<OT>::t VT;
        const int VSH = V16<OT>::sh;          // log2 elems per 16B
        const int VEC = 1 << VSH;
        const int NP  = (32 * 128) / (256 * VEC);   // 2 (bf16) / 4 (f32)
#pragma unroll
        for (int p = 0; p < NP; p++) {
            const int vid  = p * 256 + tid;
            const int lrow = vid >> (7 - VSH);      // vid / (128/VEC)
            const int vcol = vid & ((128 >> VSH) - 1);
            const long grow = bm + (lrow >> 4) * 64 + mi * 16 + (lrow & 15);
            *(VT*)&Co[grow * (long)ldC + bn + vcol * VEC] =
                *(const VT*)&sm[lrow * 128 + vcol * VEC];
        }
    }
}

template<int EPI, typename OT>
static void launch_gemm(const bf16_t* A, const bf16_t* B, OT* C,
                        int M, int Nc, int Kd, int lda, int ldb, int ldc,
                        int splitk, long partStride, float scale,
                        const float* bias, float* denom, hipStream_t s)
{
    dim3 g(M / 128, Nc / 128, splitk);
    gemm_nt<EPI, OT><<<g, 256, 0, s>>>(A, B, C, M, Nc, Kd, lda, ldb, ldc,
                                       partStride, scale, bias, denom);
}

// ---------------------------------------------------------------------------
// transpose + f32->bf16 convert: in[R x C] f32 -> out[C x R] bf16
// ---------------------------------------------------------------------------
__global__ __launch_bounds__(256)
void transpose_f2b(const float* __restrict__ in, bf16_t* __restrict__ out,
                   int R, int C)
{
    __shared__ float tile[32][33];
    const int bx = blockIdx.x * 32;  // col base in 'in'
    const int by = blockIdx.y * 32;  // row base in 'in'
    const int tx = threadIdx.x, ty = threadIdx.y;  // (32, 8)
#pragma unroll
    for (int i = 0; i < 32; i += 8)
        tile[ty + i][tx] = in[(long)(by + ty + i) * C + bx + tx];
    __syncthreads();
#pragma unroll
    for (int i = 0; i < 32; i += 8)
        out[(long)(bx + ty + i) * R + by + tx] = (bf16_t)tile[tx][ty + i];
}

// ---------------------------------------------------------------------------
// strided bf16 transpose: in[R x C] (row stride ldin) -> out[C x R]
// ---------------------------------------------------------------------------
__global__ __launch_bounds__(256)
void transpose_b2b(const bf16_t* __restrict__ in, bf16_t* __restrict__ out,
                   int R, int C, int ldin)
{
    __shared__ bf16_t tile[32][34];
    const int bx = blockIdx.x * 32;
    const int by = blockIdx.y * 32;
    const int tx = threadIdx.x, ty = threadIdx.y;  // (32, 8)
#pragma unroll
    for (int i = 0; i < 32; i += 8)
        tile[ty + i][tx] = in[(long)(by + ty + i) * ldin + bx + tx];
    __syncthreads();
#pragma unroll
    for (int i = 0; i < 32; i += 8)
        out[(long)(bx + ty + i) * R + by + tx] = tile[tx][ty + i];
}

// ---------------------------------------------------------------------------
// encoder attn-weights: out_f32[row] = P_unnorm_bf16[row] / denom[row]
// ---------------------------------------------------------------------------
__global__ __launch_bounds__(256)
void encw_norm(const bf16_t* __restrict__ P, const float* __restrict__ denom,
               float* __restrict__ out)
{
    const long row = blockIdx.x;
    const float inv = 1.0f / denom[row];
    const bf16_t* p = P + row * (long)NN;
    float* q = out + row * (long)NN;
    const int tid = threadIdx.x;
#pragma unroll
    for (int i = 0; i < 4; i++) {
        const int o = (tid + i * 256) * 8;
        bf16x8 v = *(const bf16x8*)(p + o);
        float4 lo, hi;
        lo.x = (float)v[0] * inv; lo.y = (float)v[1] * inv;
        lo.z = (float)v[2] * inv; lo.w = (float)v[3] * inv;
        hi.x = (float)v[4] * inv; hi.y = (float)v[5] * inv;
        hi.z = (float)v[6] * inv; hi.w = (float)v[7] * inv;
        *(float4*)(q + o)     = lo;
        *(float4*)(q + o + 4) = hi;
    }
}

__global__ __launch_bounds__(256)
void zero_f32(float* __restrict__ p)
{
    p[blockIdx.x * 256 + threadIdx.x] = 0.0f;
}

// ---------------------------------------------------------------------------
// LayerNorm(sum(NP partials)*rowscale? + colbias? + b) * g + be
// emits bf16 (ob) and f32 (of). one wave per row of DD=512
// ---------------------------------------------------------------------------
template<int NP, bool RS, bool CB>
__global__ __launch_bounds__(64)
void add_ln_gen(const float* __restrict__ a, long pstride,
                const float* __restrict__ rs, const float* __restrict__ cb,
                const float* __restrict__ b,
                const float* __restrict__ g, const float* __restrict__ be,
                bf16_t* __restrict__ ob, float* __restrict__ of)
{
    const long row = blockIdx.x;
    const int lane = threadIdx.x;
    const long base = row * DD + lane * 8;
    const float irs = RS ? (1.0f / rs[row]) : 1.0f;
    float v[8], s = 0.0f, s2 = 0.0f;
#pragma unroll
    for (int j = 0; j < 8; j++) {
        float t = 0.0f;
#pragma unroll
        for (int p = 0; p < NP; p++) t += a[base + j + p * pstride];
        t *= irs;
        if (CB) t += cb[lane * 8 + j];
        t += b[base + j];
        v[j] = t;
        s += t; s2 += t * t;
    }
#pragma unroll
    for (int off = 32; off > 0; off >>= 1) {
        s  += __shfl_xor(s,  off);
        s2 += __shfl_xor(s2, off);
    }
    const float mu  = s * (1.0f / DD);
    const float var = s2 * (1.0f / DD) - mu * mu;
    const float inv = rsqrtf(var + 1e-5f);
    bf16x8 o;
#pragma unroll
    for (int j = 0; j < 8; j++) {
        float r = (v[j] - mu) * inv * g[lane * 8 + j] + be[lane * 8 + j];
        o[j] = (bf16_t)r;
        of[base + j] = r;
    }
    *(bf16x8*)(ob + base) = o;
}

// ---------------------------------------------------------------------------
// use_x construction, masked scatter/gather (f32 I/O, int32 indices)
// ---------------------------------------------------------------------------
__global__ __launch_bounds__(256)
void build_usex(const float* __restrict__ x, bf16_t* __restrict__ ub,
                float* __restrict__ uf)
{
    const long i = ((long)blockIdx.x * 256 + threadIdx.x) * 4;
    const float4 v = *(const float4*)(x + i);
    *(float4*)(uf + i) = v;
    bf16x4 o = { (bf16_t)v.x, (bf16_t)v.y, (bf16_t)v.z, (bf16_t)v.w };
    *(bf16x4*)(ub + i) = o;
}

__global__ __launch_bounds__(256)
void scatter_zero(bf16_t* __restrict__ ub, float* __restrict__ uf,
                  const int* __restrict__ mn, const int* __restrict__ gi)
{
    const int i = blockIdx.x * 256 + threadIdx.x;   // grid = MM*KK/256
    const long idx = (long)mn[i >> 7] * DD + gi[i];
    ub[idx] = (bf16_t)0.0f;
    uf[idx] = 0.0f;
}

__global__ __launch_bounds__(256)
void gather_mk(const float* __restrict__ src, const int* __restrict__ mn,
               const int* __restrict__ gi, float* __restrict__ dst)
{
    const int i = blockIdx.x * 256 + threadIdx.x;
    dst[i] = src[(long)mn[i >> 7] * DD + gi[i]];
}

// head split-K combine + bias folded into the masked gather (2 partials)
__global__ __launch_bounds__(256)
void gather_head(const float* __restrict__ p1, long pstride,
                 const float* __restrict__ hb, const int* __restrict__ mn,
                 const int* __restrict__ gi, float* __restrict__ dst)
{
    const int i = blockIdx.x * 256 + threadIdx.x;
    const int col = gi[i];
    const long idx = (long)mn[i >> 7] * DD + col;
    dst[i] = p1[idx] + p1[idx + pstride] + hb[col];
}

// ---------------------------------------------------------------------------
extern "C" void kernel_launch(void* const* d_in, const int* in_sizes, int n_in,
                              void* d_out, int out_size, void* d_ws, size_t ws_size,
                              hipStream_t stream)
{
    const float* x      = (const float*)d_in[0];
    const int*   mn     = (const int*)d_in[1];
    const int*   gi     = (const int*)d_in[2];
    const float* Wq_e   = (const float*)d_in[3];
    const float* Wk_e   = (const float*)d_in[4];
    const float* Wv_e   = (const float*)d_in[5];
    const float* ln1_g  = (const float*)d_in[6];
    const float* ln1_b  = (const float*)d_in[7];
    const float* ff_W1  = (const float*)d_in[8];
    const float* ff_b1  = (const float*)d_in[9];
    const float* ff_W2  = (const float*)d_in[10];
    const float* ff_b2  = (const float*)d_in[11];
    const float* ln2_g  = (const float*)d_in[12];
    const float* ln2_b  = (const float*)d_in[13];
    const float* Wq_d   = (const float*)d_in[14];
    const float* Wk_d   = (const float*)d_in[15];
    const float* Wv_d   = (const float*)d_in[16];
    const float* ln3_g  = (const float*)d_in[17];
    const float* ln3_b  = (const float*)d_in[18];
    const float* ln4_g  = (const float*)d_in[19];
    const float* ln4_b  = (const float*)d_in[20];
    const float* head_W = (const float*)d_in[21];
    const float* head_b = (const float*)d_in[22];

    float* outf     = (float*)d_out;
    float* o_xinit  = outf;                           // [MM*KK]
    float* o_xrecon = outf + (size_t)MM * KK;         // [MM*KK]
    float* o_encw   = outf + (size_t)2 * MM * KK;     // [NN*NN]
    float* o_recon  = o_encw + (size_t)NN * NN;       // [NN*DD]

    // workspace carve-up (256B aligned) with lifetime aliasing
    char* ws = (char*)d_ws;
    size_t off = 0;
    auto alloc = [&](size_t bytes) -> void* {
        void* p = ws + off;
        off += (bytes + 255) & ~(size_t)255;
        return p;
    };
    const size_t NDb = (size_t)NN * DD * sizeof(bf16_t);   // 8 MiB
    const size_t NDf = (size_t)NN * DD * sizeof(float);    // 16 MiB
    const long   NDe = (long)NN * DD;                      // partial stride

    bf16_t* usex_b = (bf16_t*)alloc(NDb);
    bf16_t* qkv_b  = (bf16_t*)alloc((size_t)NN * 3 * DD * 2);  // 24 MiB
    bf16_t* vt_b   = (bf16_t*)alloc(NDb);
    bf16_t* hid_b  = (bf16_t*)alloc(NDb);
    float*  usex_f = (float*)alloc(NDf);
    float*  resA_f = (float*)alloc(NDf);
    float*  part_f = (float*)alloc(2 * NDf);               // 32 MiB split-K
    bf16_t* wt_qe  = (bf16_t*)alloc((size_t)DD * DD * 2);  // qe/ke/ve contiguous
    bf16_t* wt_ke  = (bf16_t*)alloc((size_t)DD * DD * 2);
    bf16_t* wt_ve  = (bf16_t*)alloc((size_t)DD * DD * 2);
    bf16_t* wt_qd  = (bf16_t*)alloc((size_t)DD * DD * 2);  // qd/kd/vd contiguous
    bf16_t* wt_kd  = (bf16_t*)alloc((size_t)DD * DD * 2);
    bf16_t* wt_vd  = (bf16_t*)alloc((size_t)DD * DD * 2);
    bf16_t* wt_h   = (bf16_t*)alloc((size_t)DD * DD * 2);
    bf16_t* w1t    = (bf16_t*)alloc((size_t)DD * FF * 2);
    bf16_t* w2t    = (bf16_t*)alloc((size_t)FF * DD * 2);
    float*  denom  = (float*)alloc((size_t)NN * sizeof(float));
    bf16_t* scores = (bf16_t*)alloc((size_t)NN * NN * 2);  // 128 MiB
    // aliases (disjoint lifetimes):
    bf16_t* t1_b   = scores;           // [NN*FF] bf16, FFN mid — attn phases done
    float*  resB_f = usex_f;           // usex_f dead after ln1; resB born at ln2
    (void)ws_size; (void)in_sizes; (void)n_in; (void)out_size;
    (void)wt_ke; (void)wt_ve; (void)wt_kd; (void)wt_vd;

    auto tr = [&](const float* in, bf16_t* o, int R, int C) {
        transpose_f2b<<<dim3(C / 32, R / 32), dim3(32, 8), 0, stream>>>(in, o, R, C);
    };
    const float SC = 0.04419417382f;  // 1/sqrt(512)

    // 0. weights -> transposed bf16 (q/k/v trios contiguous => fused-QKV B)
    tr(Wq_e, wt_qe, DD, DD);  tr(Wk_e, wt_ke, DD, DD);  tr(Wv_e, wt_ve, DD, DD);
    tr(Wq_d, wt_qd, DD, DD);  tr(Wk_d, wt_kd, DD, DD);  tr(Wv_d, wt_vd, DD, DD);
    tr(head_W, wt_h, DD, DD); tr(ff_W1, w1t, DD, FF);   tr(ff_W2, w2t, FF, DD);

    // 1. use_x (bf16 + f32) with masked zeros; x_init gather (exact f32)
    build_usex<<<NN * DD / 1024, 256, 0, stream>>>(x, usex_b, usex_f);
    scatter_zero<<<MM * KK / 256, 256, 0, stream>>>(usex_b, usex_f, mn, gi);
    gather_mk<<<MM * KK / 256, 256, 0, stream>>>(x, mn, gi, o_xinit);

    // 2. encoder attention
    //   fused QKV: [NN x 1536] = usex @ [Wq|Wk|Wv]
    launch_gemm<0, bf16_t>(usex_b, wt_qe, qkv_b,
                           NN, 3 * DD, DD, DD, DD, 3 * DD, 1, 0, 0.f, nullptr,
                           nullptr, stream);
    transpose_b2b<<<dim3(DD / 32, NN / 32), dim3(32, 8), 0, stream>>>(
        qkv_b + 2 * DD, vt_b, NN, DD, 3 * DD);        // V^T bf16 [DD x NN]
    zero_f32<<<NN / 256, 256, 0, stream>>>(denom);
    //   P_unnorm = exp(QK^T/sqrt(D)); row partial sums -> denom
    launch_gemm<4, bf16_t>(qkv_b, qkv_b + DD, scores,
                           NN, NN, DD, 3 * DD, 3 * DD, NN, 1, 0, SC, nullptr,
                           denom, stream);
    encw_norm<<<NN, 256, 0, stream>>>(scores, denom, o_encw);
    //   O_unnorm = P_unnorm @ V  (split-K=2; scale+combine in LN)
    launch_gemm<0, float>(scores, vt_b, part_f,
                          NN, DD, NN, NN, NN, DD, 2, NDe, 0.f, nullptr,
                          nullptr, stream);
    add_ln_gen<2, true, false><<<NN, 64, 0, stream>>>(
        part_f, NDe, denom, nullptr, usex_f, ln1_g, ln1_b, hid_b, resA_f);

    // 3. encoder FFN (scores dead -> t1 alias live)
    launch_gemm<3, bf16_t>(hid_b, w1t, t1_b,
                           NN, FF, DD, DD, DD, FF, 1, 0, 0.f, ff_b1,
                           nullptr, stream);
    launch_gemm<0, float>(t1_b, w2t, part_f,
                          NN, DD, FF, FF, FF, DD, 2, NDe, 0.f, nullptr,
                          nullptr, stream);
    add_ln_gen<2, false, true><<<NN, 64, 0, stream>>>(
        part_f, NDe, nullptr, ff_b2, resA_f, ln2_g, ln2_b, hid_b, resB_f);

    // 4. decoder attention (t1 dead -> scores alias live)
    launch_gemm<0, bf16_t>(hid_b, wt_qd, qkv_b,
                           NN, 3 * DD, DD, DD, DD, 3 * DD, 1, 0, 0.f, nullptr,
                           nullptr, stream);
    transpose_b2b<<<dim3(DD / 32, NN / 32), dim3(32, 8), 0, stream>>>(
        qkv_b + 2 * DD, vt_b, NN, DD, 3 * DD);
    zero_f32<<<NN / 256, 256, 0, stream>>>(denom);
    launch_gemm<4, bf16_t>(qkv_b, qkv_b + DD, scores,
                           NN, NN, DD, 3 * DD, 3 * DD, NN, 1, 0, SC, nullptr,
                           denom, stream);
    launch_gemm<0, float>(scores, vt_b, part_f,
                          NN, DD, NN, NN, NN, DD, 2, NDe, 0.f, nullptr,
                          nullptr, stream);
    add_ln_gen<2, true, false><<<NN, 64, 0, stream>>>(
        part_f, NDe, denom, nullptr, resB_f, ln3_g, ln3_b, hid_b, resA_f);

    // 5. decoder FFN (scores dead -> t1 alias live)
    launch_gemm<3, bf16_t>(hid_b, w1t, t1_b,
                           NN, FF, DD, DD, DD, FF, 1, 0, 0.f, ff_b1,
                           nullptr, stream);
    launch_gemm<0, float>(t1_b, w2t, part_f,
                          NN, DD, FF, FF, FF, DD, 2, NDe, 0.f, nullptr,
                          nullptr, stream);
    add_ln_gen<2, false, true><<<NN, 64, 0, stream>>>(
        part_f, NDe, nullptr, ff_b2, resA_f, ln4_g, ln4_b, hid_b, o_recon);

    // 6. head (split-K=2, bias+combine folded into gather)
    launch_gemm<0, float>(hid_b, wt_h, part_f,
                          NN, DD, DD, DD, DD, DD, 2, NDe, 0.f, nullptr,
                          nullptr, stream);
    gather_head<<<MM * KK / 256, 256, 0, stream>>>(part_f, NDe, head_b,
                                                   mn, gi, o_xrecon);
}